// Round 1
// baseline (908.573 us; speedup 1.0000x reference)
//
#include <hip/hip_runtime.h>

#define DD 32768
#define NN 512
#define PF 10      // design trailing dim
#define PP 8       // used columns
#define NACC 44    // 36 packed xtx + 8 xty

__device__ __forceinline__ float softplus_f(float x) {
    // stable: max(x,0) + log1p(exp(-|x|))  (matches jax.nn.softplus)
    return fmaxf(x, 0.0f) + log1pf(__expf(-fabsf(x)));
}

// One wave (64 lanes) per d. Accumulate packed-lower xtx (36) + xty (8),
// butterfly-reduce across the wave, lane 0 writes 44 floats to scratch
// (the L-region of d_out, stride 64 per d -> 16B aligned float4 stores).
__global__ __launch_bounds__(256) void k_sums(
    const float* __restrict__ y,
    const float* __restrict__ design,
    const float* __restrict__ inv_scale,
    const float* __restrict__ h1w,
    const float* __restrict__ h1b,
    float* scratch)   // = out + DD*8, NOT restrict (aliases out)
{
    const int lane = threadIdx.x & 63;
    const int d    = blockIdx.x * (blockDim.x >> 6) + (threadIdx.x >> 6);

    float acc[NACC];
#pragma unroll
    for (int k = 0; k < NACC; ++k) acc[k] = 0.0f;

    const float2* dp = (const float2*)(design + (size_t)d * (NN * PF));
    const float*  yp = y + (size_t)d * NN;

#pragma unroll 1
    for (int i = 0; i < NN / 64; ++i) {
        const int n  = i * 64 + lane;
        const int r5 = n * 5;                 // float2 index of row start (40B rows)
        float2 a0 = dp[r5 + 0];
        float2 a1 = dp[r5 + 1];
        float2 a2 = dp[r5 + 2];
        float2 a3 = dp[r5 + 3];
        const float X[8] = {a0.x, a0.y, a1.x, a1.y, a2.x, a2.y, a3.x, a3.y};

        float yv = yp[n];
        float yc = fminf(fmaxf(yv, 1e-35f), 1.0f);
        float ym = fminf(fmaxf(1.0f - yv, 1e-35f), 1.0f);
        float t  = (__logf(yc) - __logf(ym)) * 10.0f * inv_scale[n];
        float yt = fmaf(softplus_f(t), h1w[n], t) + h1b[n];

        int k = 0;
#pragma unroll
        for (int p = 0; p < PP; ++p) {
#pragma unroll
            for (int q = 0; q <= p; ++q, ++k) acc[k] = fmaf(X[p], X[q], acc[k]);
        }
#pragma unroll
        for (int p = 0; p < PP; ++p) acc[36 + p] = fmaf(X[p], yt, acc[36 + p]);
    }

#pragma unroll
    for (int off = 32; off; off >>= 1) {
#pragma unroll
        for (int k = 0; k < NACC; ++k) acc[k] += __shfl_xor(acc[k], off, 64);
    }

    if (lane == 0) {
        float4* o = (float4*)(scratch + (size_t)d * 64);
#pragma unroll
        for (int k = 0; k < 11; ++k)
            o[k] = make_float4(acc[4 * k], acc[4 * k + 1], acc[4 * k + 2], acc[4 * k + 3]);
    }
}

// One thread per d: read 44 sums, add softplus(regu) diagonal, Cholesky
// solve 8x8 SPD system for mu, write mu; then write L (overwriting the
// scratch region -- in-thread loads precede the stores, same pointer base).
__global__ __launch_bounds__(256) void k_solve(
    const float* regu_,
    const float* scale_tril_,
    float* out)     // mu at out[0..DD*8), L/scratch at out + DD*8
{
    const int d = blockIdx.x * blockDim.x + threadIdx.x;
    const float* __restrict__ regu       = regu_;
    const float* __restrict__ scale_tril = scale_tril_;
    float* mu_out = out;
    float* Lreg   = out + (size_t)DD * 8;

    float s[NACC];
    {
        const float4* ip = (const float4*)(Lreg + (size_t)d * 64);
#pragma unroll
        for (int k = 0; k < 11; ++k) {
            float4 v = ip[k];
            s[4 * k] = v.x; s[4 * k + 1] = v.y; s[4 * k + 2] = v.z; s[4 * k + 3] = v.w;
        }
    }

    float A[PP][PP];   // lower triangle used
    {
        int k = 0;
#pragma unroll
        for (int p = 0; p < PP; ++p)
#pragma unroll
            for (int q = 0; q <= p; ++q, ++k) A[p][q] = s[k];
    }
    float b[PP];
#pragma unroll
    for (int p = 0; p < PP; ++p) b[p] = s[36 + p];
#pragma unroll
    for (int p = 0; p < PP; ++p) A[p][p] += softplus_f(regu[(size_t)d * PP + p]);

    // Cholesky factorization in the lower triangle of A
    float dinv[PP];
#pragma unroll
    for (int j = 0; j < PP; ++j) {
        float v = A[j][j];
#pragma unroll
        for (int k = 0; k < j; ++k) v -= A[j][k] * A[j][k];
        float lj = sqrtf(v);
        float iv = 1.0f / lj;
        A[j][j] = lj;
        dinv[j] = iv;
#pragma unroll
        for (int i = j + 1; i < PP; ++i) {
            float u = A[i][j];
#pragma unroll
            for (int k = 0; k < j; ++k) u -= A[i][k] * A[j][k];
            A[i][j] = u * iv;
        }
    }
    // forward: L z = b
    float z[PP];
#pragma unroll
    for (int i = 0; i < PP; ++i) {
        float v = b[i];
#pragma unroll
        for (int k = 0; k < i; ++k) v -= A[i][k] * z[k];
        z[i] = v * dinv[i];
    }
    // backward: L^T m = z
    float m[PP];
#pragma unroll
    for (int i = PP - 1; i >= 0; --i) {
        float v = z[i];
#pragma unroll
        for (int k = i + 1; k < PP; ++k) v -= A[k][i] * m[k];
        m[i] = v * dinv[i];
    }

    {
        float4* om = (float4*)(mu_out + (size_t)d * PP);
        om[0] = make_float4(m[0], m[1], m[2], m[3]);
        om[1] = make_float4(m[4], m[5], m[6], m[7]);
    }

    // L output: scatter packed-tril scale_tril into 8x8 lower-triangular
    float st[36];
    {
        const float4* sp = (const float4*)(scale_tril + (size_t)d * 36);
#pragma unroll
        for (int k = 0; k < 9; ++k) {
            float4 v = sp[k];
            st[4 * k] = v.x; st[4 * k + 1] = v.y; st[4 * k + 2] = v.z; st[4 * k + 3] = v.w;
        }
    }
    {
        float4* ol = (float4*)(Lreg + (size_t)d * 64);
#pragma unroll
        for (int r = 0; r < 8; ++r) {
            float row[8];
#pragma unroll
            for (int c = 0; c < 8; ++c)
                row[c] = (c <= r) ? st[(r * (r + 1)) / 2 + c] : 0.0f;
            ol[2 * r + 0] = make_float4(row[0], row[1], row[2], row[3]);
            ol[2 * r + 1] = make_float4(row[4], row[5], row[6], row[7]);
        }
    }
}

extern "C" void kernel_launch(void* const* d_in, const int* in_sizes, int n_in,
                              void* d_out, int out_size, void* d_ws, size_t ws_size,
                              hipStream_t stream) {
    const float* y          = (const float*)d_in[0];
    const float* design     = (const float*)d_in[1];
    const float* inv_scale  = (const float*)d_in[2];
    const float* h1w        = (const float*)d_in[3];
    const float* h1b        = (const float*)d_in[4];
    const float* scale_tril = (const float*)d_in[5];
    const float* regu       = (const float*)d_in[6];
    // d_in[7] = target_label (always 0 -> p = 8), unused

    float* out     = (float*)d_out;
    float* scratch = out + (size_t)DD * 8;   // L region doubles as scratch

    hipLaunchKernelGGL(k_sums, dim3(DD / 4), dim3(256), 0, stream,
                       y, design, inv_scale, h1w, h1b, scratch);
    hipLaunchKernelGGL(k_solve, dim3(DD / 256), dim3(256), 0, stream,
                       regu, scale_tril, out);
}